// Round 4
// baseline (7393.979 us; speedup 1.0000x reference)
//
#include <hip/hip_runtime.h>

// ObservationTransformer forward on MI355X (gfx950).
// Runtime dtype dispatch: detector decides whether float inputs are fp32 or
// bf16 (device flag in ws; deterministic, graph-safe). All raw-input reads go
// through gload(); weights/params are canonicalized to bf16 in ws.
// Layer offsets are applied ON DEVICE (element units) since width is runtime.
// ws footprint: 96 MB (round-3 diag proved ws >= 96 MB).

typedef unsigned short u16;
typedef __attribute__((ext_vector_type(8))) short s16x8;      // MFMA bf16 A/B fragment
typedef __attribute__((ext_vector_type(8))) unsigned short u16x8;
typedef __attribute__((ext_vector_type(4))) float f32x4;      // MFMA C/D fragment

#define MFMA16(a, b, c) __builtin_amdgcn_mfma_f32_16x16x32_bf16((a), (b), (c), 0, 0, 0)

__device__ __forceinline__ float b2f(u16 u) {
  union { unsigned int i; float f; } v; v.i = ((unsigned int)u) << 16; return v.f;
}
__device__ __forceinline__ u16 f2b(float f) {
  unsigned int x = __float_as_uint(f);
  return (u16)((x + 0x7fffu + ((x >> 16) & 1u)) >> 16);  // RNE
}
// dtype-aware input load, index in ELEMENTS
__device__ __forceinline__ float gload(const void* p, size_t i, int f32) {
  return f32 ? ((const float*)p)[i] : b2f(((const u16*)p)[i]);
}

// ---------------------------------------------------------------------------
// Detect input dtype from embed bits. fp32 -> odd u16s are random mantissa
// bits -> max |bf16(u16)| over 64K samples is huge w.p. ~1. bf16 -> max ~0.12.
__global__ __launch_bounds__(256) void detect_dtype(const u16* __restrict__ emb,
                                                    int* __restrict__ flag) {
  __shared__ float red[4];
  float m = 0.f;
  for (int i = threadIdx.x; i < 65536; i += 256) {
    float v = b2f(emb[i]);
    float a = fabsf(v);
    if (!(a == a)) a = 1e30f;          // NaN -> huge
    m = fmaxf(m, a);
  }
  m = fmaxf(m, __shfl_xor(m, 32)); m = fmaxf(m, __shfl_xor(m, 16));
  m = fmaxf(m, __shfl_xor(m, 8));  m = fmaxf(m, __shfl_xor(m, 4));
  m = fmaxf(m, __shfl_xor(m, 2));  m = fmaxf(m, __shfl_xor(m, 1));
  int wave = threadIdx.x >> 6;
  if ((threadIdx.x & 63) == 0) red[wave] = m;
  __syncthreads();
  if (threadIdx.x == 0) {
    float mm = fmaxf(fmaxf(red[0], red[1]), fmaxf(red[2], red[3]));
    flag[0] = (mm > 1e6f) ? 1 : 0;     // 1 = inputs are fp32
  }
}

// ---------------------------------------------------------------------------
__global__ __launch_bounds__(256) void embed_pe(const int* __restrict__ x,
                                                const void* __restrict__ emb,
                                                float* __restrict__ h,
                                                const int* __restrict__ fl) {
  const int f32 = *fl;
  int p = blockIdx.x * 256 + threadIdx.x;     // 8*1024*512
  int i = p & 511;
  int l = (p >> 9) & 1023;
  int b = p >> 19;
  int tok = x[b * 1024 + l];
  float e0 = gload(emb, (size_t)tok * 1024 + 2 * i, f32);
  float e1 = gload(emb, (size_t)tok * 1024 + 2 * i + 1, f32);
  float div = powf(10000.0f, (float)(2 * i) * (1.0f / 1024.0f));
  float ang = (float)(l + 1) / div;
  size_t o = (size_t)(b * 1024 + l) * 1024 + 2 * i;
  h[o] = e0 * 32.0f + sinf(ang);
  h[o + 1] = e1 * 32.0f + cosf(ang);
}

// ---------------------------------------------------------------------------
// QKV pack (layer offset on device): pb[n*1024+k]; which=n>>10, h=(n>>6)&15, d=n&63
__global__ __launch_bounds__(256) void pack_qkv(const void* __restrict__ wq,
                                                const void* __restrict__ wk,
                                                const void* __restrict__ wv,
                                                u16* __restrict__ pb, int layer,
                                                const int* __restrict__ fl) {
  const int f32 = *fl;
  const size_t lo = (size_t)layer * 1048576;
  int idx = blockIdx.x * 256 + threadIdx.x;   // grid 12288 -> 3145728
  int n = idx >> 10, k = idx & 1023;
  int which = n >> 10, hh = (n >> 6) & 15, d = n & 63;
  const void* w = which == 0 ? wq : (which == 1 ? wk : wv);
  pb[idx] = f2b(gload(w, lo + (size_t)hh * 65536 + k * 64 + d, f32));
}

// Transpose pack (K fixed 1024), element offset eoff applied on device:
// dst[n*1024+k] = src[eoff + k*N + n]
__global__ __launch_bounds__(256) void pack_t(const void* __restrict__ src,
                                              u16* __restrict__ dst, int N, int total,
                                              long long eoff,
                                              const int* __restrict__ fl) {
  const int f32 = *fl;
  int idx = blockIdx.x * 256 + threadIdx.x;
  if (idx >= total) return;
  int n = idx >> 10, k = idx & 1023;
  dst[idx] = f2b(gload(src, (size_t)eoff + (size_t)k * N + n, f32));
}

// Pack all small params -> canonical bf16, once.
// u16 offsets: WO_B 0 | LN1S 6144 | LN1B 12288 | FFB1 18432 | FFB2 43008
//              LN2S 49152 | LN2B 55296 | OW 61440 | OB 77824 | total 77840
__global__ __launch_bounds__(256) void pack_params(
    const void* wob, const void* l1s, const void* l1b, const void* fb1,
    const void* fb2, const void* l2s, const void* l2b, const void* ow,
    const void* ob, u16* __restrict__ dst, const int* __restrict__ fl) {
  const int f32 = *fl;
  int idx = blockIdx.x * 256 + threadIdx.x;
  if (idx >= 77840) return;
  float v;
  if      (idx < 6144)  v = gload(wob, idx, f32);
  else if (idx < 12288) v = gload(l1s, idx - 6144, f32);
  else if (idx < 18432) v = gload(l1b, idx - 12288, f32);
  else if (idx < 43008) v = gload(fb1, idx - 18432, f32);
  else if (idx < 49152) v = gload(fb2, idx - 43008, f32);
  else if (idx < 55296) v = gload(l2s, idx - 49152, f32);
  else if (idx < 61440) v = gload(l2b, idx - 55296, f32);
  else if (idx < 77824) v = gload(ow,  idx - 61440, f32);
  else                  v = gload(ob,  idx - 77824, f32);
  dst[idx] = f2b(v);
}

// ---------------------------------------------------------------------------
// GEMM: C[M,N] = A[M,K] * Bt[N,K]^T ; 128x128 tile, BK=32, 4 waves (2x2 of 64x64).
// AF32: A fp32 (bf16-converted during staging). MODE 1: outf=C+bias (fp32)
// MODE 2: o0=bf16(relu(C+bias))  MODE 3: per-batch QKV scatter (v transposed)
// MODE 4: outf += C
template <int AF32, int MODE>
__global__ __launch_bounds__(256) void gemm_t(
    const void* __restrict__ Avoid, const u16* __restrict__ Bt, int K, int N,
    const u16* __restrict__ bias, float* __restrict__ outf,
    u16* __restrict__ o0, u16* __restrict__ o1, u16* __restrict__ o2) {
  __shared__ __align__(16) u16 Al[4096];
  __shared__ __align__(16) u16 Bl[4096];
  const int tid = threadIdx.x;
  const int wave = tid >> 6, lane = tid & 63;
  const int quad = lane >> 4, ln = lane & 15;
  const int bm = blockIdx.y, bn = blockIdx.x;
  const int wr = wave >> 1, wc = wave & 1;
  const int e0 = tid * 8, e1 = 2048 + tid * 8;
  const int r0 = e0 >> 5, c0 = e0 & 31;
  const int r1 = e1 >> 5, c1 = e1 & 31;
  const float* Af = (const float*)Avoid;
  const u16*  Ab = (const u16*)Avoid;

  f32x4 acc[4][4] = {};
  for (int kt = 0; kt < (K >> 5); ++kt) {
    const int k0 = kt * 32;
    u16x8 wa0, wa1;
    if (AF32) {
      const float* p0 = Af + (size_t)(bm * 128 + r0) * K + k0 + c0;
      const float* p1 = Af + (size_t)(bm * 128 + r1) * K + k0 + c1;
      f32x4 x0 = *(const f32x4*)p0, x1 = *(const f32x4*)(p0 + 4);
      f32x4 y0 = *(const f32x4*)p1, y1 = *(const f32x4*)(p1 + 4);
#pragma unroll
      for (int j = 0; j < 4; ++j) {
        wa0[j] = f2b(x0[j]); wa0[j + 4] = f2b(x1[j]);
        wa1[j] = f2b(y0[j]); wa1[j + 4] = f2b(y1[j]);
      }
    } else {
      wa0 = *(const u16x8*)(Ab + (size_t)(bm * 128 + r0) * K + k0 + c0);
      wa1 = *(const u16x8*)(Ab + (size_t)(bm * 128 + r1) * K + k0 + c1);
    }
    u16x8 wb0 = *(const u16x8*)(Bt + (size_t)(bn * 128 + r0) * K + k0 + c0);
    u16x8 wb1 = *(const u16x8*)(Bt + (size_t)(bn * 128 + r1) * K + k0 + c1);
    __syncthreads();
    *(u16x8*)(Al + e0) = wa0; *(u16x8*)(Al + e1) = wa1;
    *(u16x8*)(Bl + e0) = wb0; *(u16x8*)(Bl + e1) = wb1;
    __syncthreads();
    s16x8 af[4], bf[4];
#pragma unroll
    for (int mt = 0; mt < 4; ++mt)
      af[mt] = *(const s16x8*)(Al + (wr * 64 + mt * 16 + ln) * 32 + quad * 8);
#pragma unroll
    for (int nt = 0; nt < 4; ++nt)
      bf[nt] = *(const s16x8*)(Bl + (wc * 64 + nt * 16 + ln) * 32 + quad * 8);
#pragma unroll
    for (int mt = 0; mt < 4; ++mt)
#pragma unroll
      for (int nt = 0; nt < 4; ++nt)
        acc[mt][nt] = MFMA16(af[mt], bf[nt], acc[mt][nt]);
  }

#pragma unroll
  for (int mt = 0; mt < 4; ++mt) {
    int rowb = bm * 128 + wr * 64 + mt * 16 + quad * 4;
#pragma unroll
    for (int nt = 0; nt < 4; ++nt) {
      int col = bn * 128 + wc * 64 + nt * 16 + ln;
      f32x4 c = acc[mt][nt];
      if (MODE == 3) {
        int which = col >> 10, hh = (col >> 6) & 15, d = col & 63;
#pragma unroll
        for (int r = 0; r < 4; ++r) {
          int l = rowb + r;
          if (which == 0)      o0[(hh * 1024 + l) * 64 + d] = f2b(c[r]);
          else if (which == 1) o1[(hh * 1024 + l) * 64 + d] = f2b(c[r]);
          else                 o2[(hh * 64 + d) * 1024 + l] = f2b(c[r]);  // vT
        }
      } else if (MODE == 1) {
        float bv = b2f(bias[col]);
#pragma unroll
        for (int r = 0; r < 4; ++r)
          outf[(size_t)(rowb + r) * N + col] = c[r] + bv;
      } else if (MODE == 2) {
        float bv = b2f(bias[col]);
#pragma unroll
        for (int r = 0; r < 4; ++r) {
          float y = c[r] + bv;
          o0[(size_t)(rowb + r) * N + col] = f2b(y > 0.0f ? y : 0.0f);
        }
      } else {
#pragma unroll
        for (int r = 0; r < 4; ++r)
          outf[(size_t)(rowb + r) * N + col] += c[r];
      }
    }
  }
}

// ---------------------------------------------------------------------------
// Flash attention, per-batch: grid (qt=16, h=16), 256 thr.
#define AST 80
__global__ __launch_bounds__(256) void attn(const u16* __restrict__ q,
                                            const u16* __restrict__ kb,
                                            const u16* __restrict__ vt,
                                            u16* __restrict__ ctx, int b) {
  const int qt = blockIdx.x, hh = blockIdx.y;
  __shared__ __align__(16) u16 Kl[64 * AST];
  __shared__ __align__(16) u16 Vl[64 * AST];
  __shared__ __align__(16) u16 Pl[64 * AST];
  const int tid = threadIdx.x, wave = tid >> 6, lane = tid & 63;
  const int quad = lane >> 4, ln = lane & 15;
  const u16* qbh = q + hh * 65536;
  const u16* kbh = kb + hh * 65536;
  const u16* vbh = vt + hh * 65536;

  const int qrow = qt * 64 + wave * 16 + ln;
  s16x8 qf0 = *(const s16x8*)(qbh + qrow * 64 + quad * 8);
  s16x8 qf1 = *(const s16x8*)(qbh + qrow * 64 + 32 + quad * 8);

  f32x4 o[4] = {};
  float mrun[4] = {-1e30f, -1e30f, -1e30f, -1e30f};
  float lrun[4] = {0.f, 0.f, 0.f, 0.f};

  for (int kt = 0; kt < 16; ++kt) {
    __syncthreads();
#pragma unroll
    for (int r2 = 0; r2 < 2; ++r2) {
      int off = r2 * 2048 + tid * 8;
      int row = off >> 6, col = off & 63;
      u16x8 kv = *(const u16x8*)(kbh + kt * 4096 + off);
      *(u16x8*)(Kl + row * AST + col) = kv;
      u16x8 vv = *(const u16x8*)(vbh + row * 1024 + kt * 64 + col);
      *(u16x8*)(Vl + row * AST + col) = vv;
    }
    __syncthreads();

    f32x4 s[4] = {};
#pragma unroll
    for (int nt = 0; nt < 4; ++nt) {
      s16x8 kf0 = *(const s16x8*)(Kl + (nt * 16 + ln) * AST + quad * 8);
      s16x8 kf1 = *(const s16x8*)(Kl + (nt * 16 + ln) * AST + 32 + quad * 8);
      s[nt] = MFMA16(qf0, kf0, s[nt]);
      s[nt] = MFMA16(qf1, kf1, s[nt]);
    }

    float mnew[4], alpha[4], rowsum[4];
#pragma unroll
    for (int r = 0; r < 4; ++r) {
      float v = fmaxf(fmaxf(s[0][r], s[1][r]), fmaxf(s[2][r], s[3][r]));
      v = fmaxf(v, __shfl_xor(v, 1)); v = fmaxf(v, __shfl_xor(v, 2));
      v = fmaxf(v, __shfl_xor(v, 4)); v = fmaxf(v, __shfl_xor(v, 8));
      v *= 0.125f;
      mnew[r] = fmaxf(mrun[r], v);
      alpha[r] = __expf(mrun[r] - mnew[r]);
      mrun[r] = mnew[r];
      rowsum[r] = 0.f;
    }
#pragma unroll
    for (int nt = 0; nt < 4; ++nt)
#pragma unroll
      for (int r = 0; r < 4; ++r) {
        float p = __expf(s[nt][r] * 0.125f - mnew[r]);
        rowsum[r] += p;
        Pl[(wave * 16 + quad * 4 + r) * AST + nt * 16 + ln] = f2b(p);
      }
#pragma unroll
    for (int r = 0; r < 4; ++r) {
      float t = rowsum[r];
      t += __shfl_xor(t, 1); t += __shfl_xor(t, 2);
      t += __shfl_xor(t, 4); t += __shfl_xor(t, 8);
      lrun[r] = lrun[r] * alpha[r] + t;
      o[0][r] *= alpha[r]; o[1][r] *= alpha[r];
      o[2][r] *= alpha[r]; o[3][r] *= alpha[r];
    }
    __syncthreads();

#pragma unroll
    for (int ks = 0; ks < 2; ++ks) {
      s16x8 pf = *(const s16x8*)(Pl + (wave * 16 + ln) * AST + ks * 32 + quad * 8);
#pragma unroll
      for (int dt = 0; dt < 4; ++dt) {
        s16x8 vf = *(const s16x8*)(Vl + (dt * 16 + ln) * AST + ks * 32 + quad * 8);
        o[dt] = MFMA16(pf, vf, o[dt]);
      }
    }
  }

#pragma unroll
  for (int dt = 0; dt < 4; ++dt)
#pragma unroll
    for (int r = 0; r < 4; ++r) {
      int l = qt * 64 + wave * 16 + quad * 4 + r;
      ctx[((size_t)(b * 1024 + l)) * 1024 + hh * 64 + dt * 16 + ln] = f2b(o[dt][r] / lrun[r]);
    }
}

// ---------------------------------------------------------------------------
__device__ __forceinline__ float block_sum(float v, float* red, int wave, int lane) {
  v += __shfl_xor(v, 32); v += __shfl_xor(v, 16); v += __shfl_xor(v, 8);
  v += __shfl_xor(v, 4);  v += __shfl_xor(v, 2);  v += __shfl_xor(v, 1);
  if (lane == 0) red[wave] = v;
  __syncthreads();
  float s = red[0] + red[1] + red[2] + red[3];
  __syncthreads();
  return s;
}

__global__ __launch_bounds__(256) void ln_kernel(float* __restrict__ h,
                                                 const float* __restrict__ delta,
                                                 const u16* __restrict__ sc,
                                                 const u16* __restrict__ bs) {
  __shared__ float red[4];
  const int row = blockIdx.x, t = threadIdx.x;
  const int wave = t >> 6, lane = t & 63;
  float* hr = h + (size_t)row * 1024;
  const float* dr = delta + (size_t)row * 1024;
  float x0 = hr[t] + dr[t];
  float x1 = hr[t + 256] + dr[t + 256];
  float x2 = hr[t + 512] + dr[t + 512];
  float x3 = hr[t + 768] + dr[t + 768];
  float mean = block_sum(x0 + x1 + x2 + x3, red, wave, lane) * (1.0f / 1024.0f);
  float d0 = x0 - mean, d1 = x1 - mean, d2 = x2 - mean, d3 = x3 - mean;
  float var = block_sum(d0 * d0 + d1 * d1 + d2 * d2 + d3 * d3, red, wave, lane) * (1.0f / 1024.0f);
  float inv = rsqrtf(var + 1e-5f);
  hr[t]       = d0 * inv * b2f(sc[t])       + b2f(bs[t]);
  hr[t + 256] = d1 * inv * b2f(sc[t + 256]) + b2f(bs[t + 256]);
  hr[t + 512] = d2 * inv * b2f(sc[t + 512]) + b2f(bs[t + 512]);
  hr[t + 768] = d3 * inv * b2f(sc[t + 768]) + b2f(bs[t + 768]);
}

// ---------------------------------------------------------------------------
__global__ __launch_bounds__(128) void head_kernel(const float* __restrict__ h,
                                                   const u16* __restrict__ ow,
                                                   const u16* __restrict__ ob,
                                                   void* __restrict__ out,
                                                   const int* __restrict__ fl) {
  const int t = threadIdx.x;          // 8 b x 16 actions
  const int b = t >> 4, a = t & 15;
  const float* hr = h + ((size_t)(b * 1024 + 1023)) * 1024;
  float acc = 0.f;
  for (int d = 0; d < 1024; ++d) acc += hr[d] * b2f(ow[d * 16 + a]);
  acc += b2f(ob[a]);
  float m = acc;
  m = fmaxf(m, __shfl_xor(m, 1)); m = fmaxf(m, __shfl_xor(m, 2));
  m = fmaxf(m, __shfl_xor(m, 4)); m = fmaxf(m, __shfl_xor(m, 8));
  float e = __expf(acc - m);
  float s = e;
  s += __shfl_xor(s, 1); s += __shfl_xor(s, 2);
  s += __shfl_xor(s, 4); s += __shfl_xor(s, 8);
  float r = acc - m - logf(s);
  if (*fl) ((float*)out)[t] = r;      // fp32 problem -> fp32 output
  else     ((u16*)out)[t] = f2b(r);   // bf16 problem -> bf16 output
}

__global__ void diag_kernel(u16* out, float val) { out[threadIdx.x] = f2b(val); }

// ---------------------------------------------------------------------------
extern "C" void kernel_launch(void* const* d_in, const int* in_sizes, int n_in,
                              void* d_out, int out_size, void* d_ws, size_t ws_size,
                              hipStream_t stream) {
  const int* x      = (const int*)d_in[0];
  const void* embed = d_in[2];
  const void* Wq    = d_in[3];
  const void* Wk    = d_in[4];
  const void* Wv    = d_in[5];
  const void* Wo_w  = d_in[6];
  const void* Wo_b  = d_in[7];
  const void* ln1s  = d_in[8];
  const void* ln1b  = d_in[9];
  const void* ffw1  = d_in[10];
  const void* ffb1  = d_in[11];
  const void* ffw2  = d_in[12];
  const void* ffb2  = d_in[13];
  const void* ln2s  = d_in[14];
  const void* ln2b  = d_in[15];
  const void* ow    = d_in[16];
  const void* ob    = d_in[17];

  const size_t NEEDED = 100663296;   // 96 MB
  if (ws_size < NEEDED) {
    diag_kernel<<<1, 128, 0, stream>>>((u16*)d_out, (float)(ws_size >> 20));
    return;
  }

  char* ws = (char*)d_ws;
  float* hM   = (float*)(ws + 0);
  float* att  = (float*)(ws + 33554432);
  u16* pBa    = (u16*)(ws + 67108864);
  u16* params = (u16*)(ws + 75497472);
  int* flag   = (int*)(ws + 77590528);
  u16* qb     = (u16*)(ws + 77594624);
  u16* pBb    = (u16*)(ws + 77594624);   // overlays qb (disjoint in time)
  u16* kbuf   = (u16*)(ws + 79691776);
  u16* vtb    = (u16*)(ws + 81788928);
  u16* ctx    = (u16*)(ws + 83886080);
  u16* ffA    = (u16*)(ws + 83886080);   // overlays ctx (disjoint in time)

  const int WO_B = 0, LN1S = 6144, LN1B = 12288, FFB1 = 18432, FFB2 = 43008,
            LN2S = 49152, LN2B = 55296, OW = 61440, OB = 77824;

  detect_dtype<<<1, 256, 0, stream>>>((const u16*)embed, flag);
  pack_params<<<305, 256, 0, stream>>>(Wo_b, ln1s, ln1b, ffb1, ffb2, ln2s, ln2b,
                                       ow, ob, params, flag);
  embed_pe<<<16384, 256, 0, stream>>>(x, embed, hM, flag);

  for (int i = 0; i < 6; ++i) {
    // ---- attention ----
    pack_qkv<<<12288, 256, 0, stream>>>(Wq, Wk, Wv, pBa, i, flag);
    for (int b = 0; b < 8; ++b) {
      gemm_t<1, 3><<<dim3(24, 8), 256, 0, stream>>>(hM + (size_t)b * 1048576, pBa, 1024,
                                                    3072, nullptr, nullptr, qb, kbuf, vtb);
      attn<<<dim3(16, 16), 256, 0, stream>>>(qb, kbuf, vtb, ctx, b);
    }
    pack_t<<<4096, 256, 0, stream>>>(Wo_w, pBa, 1024, 1048576, (long long)i * 1048576, flag);
    gemm_t<0, 1><<<dim3(8, 64), 256, 0, stream>>>(ctx, pBa, 1024, 1024, params + WO_B + i * 1024,
                                                  att, nullptr, nullptr, nullptr);
    ln_kernel<<<8192, 256, 0, stream>>>(hM, att, params + LN1S + i * 1024,
                                        params + LN1B + i * 1024);

    // ---- feed-forward, 4 column-chunks of 1024 ----
    pack_t<<<16384, 256, 0, stream>>>(ffw1, pBa, 4096, 4194304, (long long)i * 4194304, flag);
    for (int c = 0; c < 4; ++c) {
      gemm_t<1, 2><<<dim3(8, 64), 256, 0, stream>>>(hM, pBa + (size_t)c * 1048576, 1024, 1024,
                                                    params + FFB1 + i * 4096 + c * 1024,
                                                    nullptr, ffA, nullptr, nullptr);
      pack_t<<<4096, 256, 0, stream>>>(ffw2, pBb, 1024, 1048576,
                                       (long long)i * 4194304 + (long long)c * 1048576, flag);
      if (c == 0)
        gemm_t<0, 1><<<dim3(8, 64), 256, 0, stream>>>(ffA, pBb, 1024, 1024,
                                                      params + FFB2 + i * 1024,
                                                      att, nullptr, nullptr, nullptr);
      else
        gemm_t<0, 4><<<dim3(8, 64), 256, 0, stream>>>(ffA, pBb, 1024, 1024, nullptr,
                                                      att, nullptr, nullptr, nullptr);
    }
    ln_kernel<<<8192, 256, 0, stream>>>(hM, att, params + LN2S + i * 1024,
                                        params + LN2B + i * 1024);
  }

  head_kernel<<<1, 128, 0, stream>>>(hM, params + OW, params + OB, d_out, flag);
}

// Round 5
// 3558.765 us; speedup vs baseline: 2.0777x; 2.0777x over previous
//
#include <hip/hip_runtime.h>

// ObservationTransformer forward on MI355X (gfx950).
// Inputs are fp32 (confirmed R4 by runtime detector; detector kept for safety).
// Residual stream fp32 + bf16 shadow; all GEMMs bf16 MFMA with m97-style
// global_load_lds staging. Weights packed (coalesced LDS-tiled transpose) to
// B^T [N][K] bf16 once per call. ws footprint ~353 MiB (ws is ~500 MiB).

typedef unsigned short u16;
typedef __attribute__((ext_vector_type(8))) short s16x8;      // MFMA bf16 A/B frag
typedef __attribute__((ext_vector_type(8))) unsigned short u16x8;
typedef __attribute__((ext_vector_type(4))) unsigned short u16x4;
typedef __attribute__((ext_vector_type(4))) float f32x4;      // MFMA C/D frag

#define MFMA16(a, b, c) __builtin_amdgcn_mfma_f32_16x16x32_bf16((a), (b), (c), 0, 0, 0)

__device__ __forceinline__ float b2f(u16 u) {
  union { unsigned int i; float f; } v; v.i = ((unsigned int)u) << 16; return v.f;
}
__device__ __forceinline__ u16 f2b(float f) {
  unsigned int x = __float_as_uint(f);
  return (u16)((x + 0x7fffu + ((x >> 16) & 1u)) >> 16);  // RNE
}
__device__ __forceinline__ float gload(const void* p, size_t i, int f32) {
  return f32 ? ((const float*)p)[i] : b2f(((const u16*)p)[i]);
}
// async global->LDS, 16B/lane; LDS base wave-uniform (HW: base + lane*16)
__device__ __forceinline__ void gl_lds16(const void* g, void* l) {
  __builtin_amdgcn_global_load_lds((const __attribute__((address_space(1))) void*)g,
                                   (__attribute__((address_space(3))) void*)l, 16, 0, 0);
}

// ---------------------------------------------------------------------------
// dtype detector (R4-verified): fp32 inputs make u16-halves decode to huge bf16.
__global__ __launch_bounds__(256) void detect_dtype(const u16* __restrict__ emb,
                                                    int* __restrict__ flag) {
  __shared__ float red[4];
  float m = 0.f;
  for (int i = threadIdx.x; i < 65536; i += 256) {
    float a = fabsf(b2f(emb[i]));
    if (!(a == a)) a = 1e30f;
    m = fmaxf(m, a);
  }
  m = fmaxf(m, __shfl_xor(m, 32)); m = fmaxf(m, __shfl_xor(m, 16));
  m = fmaxf(m, __shfl_xor(m, 8));  m = fmaxf(m, __shfl_xor(m, 4));
  m = fmaxf(m, __shfl_xor(m, 2));  m = fmaxf(m, __shfl_xor(m, 1));
  int wave = threadIdx.x >> 6;
  if ((threadIdx.x & 63) == 0) red[wave] = m;
  __syncthreads();
  if (threadIdx.x == 0)
    flag[0] = (fmaxf(fmaxf(red[0], red[1]), fmaxf(red[2], red[3])) > 1e6f) ? 1 : 0;
}

// ---------------------------------------------------------------------------
// Embedding + positional encoding -> fp32 master + bf16 shadow
__global__ __launch_bounds__(256) void embed_pe(const int* __restrict__ x,
                                                const void* __restrict__ emb,
                                                float* __restrict__ h,
                                                u16* __restrict__ hb,
                                                const int* __restrict__ fl) {
  const int f32 = *fl;
  int p = blockIdx.x * 256 + threadIdx.x;     // 8*1024*512
  int i = p & 511;
  int l = (p >> 9) & 1023;
  int b = p >> 19;
  int tok = x[b * 1024 + l];
  float e0 = gload(emb, (size_t)tok * 1024 + 2 * i, f32);
  float e1 = gload(emb, (size_t)tok * 1024 + 2 * i + 1, f32);
  float div = powf(10000.0f, (float)(2 * i) * (1.0f / 1024.0f));
  float ang = (float)(l + 1) / div;
  float h0 = e0 * 32.0f + sinf(ang);
  float h1 = e1 * 32.0f + cosf(ang);
  size_t o = (size_t)(b * 1024 + l) * 1024 + 2 * i;
  h[o] = h0; h[o + 1] = h1;
  hb[o] = f2b(h0); hb[o + 1] = f2b(h1);
}

// ---------------------------------------------------------------------------
// Coalesced LDS-tiled weight pack, all 6 layers, 64x64 tiles -> bf16 B^T.
// Per-layer pack layout (u16 elems, stride 12582912):
//   QKV [3072][1024] @0 | Wo^T [1024][1024] @3145728
//   ff1^T [4096][1024] @4194304 | ff2^T [1024][4096] @8388608
// mode 0: QKV  grid(16, 48, 6)   mode 1: Wo  grid(16, 16, 6)
// mode 2: ff1  grid(16, 64, 6)   mode 3: ff2 grid(64, 16, 6)
__global__ __launch_bounds__(256) void pack6(const void* __restrict__ wq,
                                             const void* __restrict__ wk,
                                             const void* __restrict__ wv,
                                             const void* __restrict__ wo,
                                             const void* __restrict__ f1,
                                             const void* __restrict__ f2,
                                             u16* __restrict__ pb, int mode,
                                             const int* __restrict__ fl) {
  __shared__ __align__(16) u16 T[64 * 80];
  const int f32 = *fl;
  const int kt = blockIdx.x, yy = blockIdx.y, layer = blockIdx.z;
  const int t = threadIdx.x;
  const void* src;
  size_t sbase, dbase;
  int sstride, dstride;
  u16* dst = pb + (size_t)layer * 12582912;
  if (mode == 0) {
    int which = yy >> 4, h = yy & 15;
    src = which == 0 ? wq : (which == 1 ? wk : wv);
    sbase = (size_t)layer * 1048576 + (size_t)h * 65536 + (size_t)kt * 64 * 64;
    sstride = 64;
    dbase = ((size_t)(which * 1024 + h * 64)) * 1024 + kt * 64;
    dstride = 1024;
  } else if (mode == 1) {
    src = wo;
    sbase = (size_t)layer * 1048576 + (size_t)kt * 64 * 1024 + yy * 64;
    sstride = 1024;
    dbase = 3145728 + (size_t)yy * 64 * 1024 + kt * 64;
    dstride = 1024;
  } else if (mode == 2) {
    src = f1;
    sbase = (size_t)layer * 4194304 + (size_t)kt * 64 * 4096 + yy * 64;
    sstride = 4096;
    dbase = 4194304 + (size_t)yy * 64 * 1024 + kt * 64;
    dstride = 1024;
  } else {
    src = f2;
    sbase = (size_t)layer * 4194304 + (size_t)kt * 64 * 1024 + yy * 64;
    sstride = 1024;
    dbase = 8388608 + (size_t)yy * 64 * 4096 + kt * 64;
    dstride = 4096;
  }
  // read 64(k) x 64(n) tile coalesced, store transposed T[n][k]
#pragma unroll
  for (int p = 0; p < 4; ++p) {
    int kk = p * 16 + (t >> 4), nn0 = (t & 15) * 4;
    size_t s = sbase + (size_t)kk * sstride + nn0;
    float v0, v1, v2, v3;
    if (f32) {
      f32x4 xv = *(const f32x4*)((const float*)src + s);
      v0 = xv[0]; v1 = xv[1]; v2 = xv[2]; v3 = xv[3];
    } else {
      u16x4 xv = *(const u16x4*)((const u16*)src + s);
      v0 = b2f(xv[0]); v1 = b2f(xv[1]); v2 = b2f(xv[2]); v3 = b2f(xv[3]);
    }
    T[(nn0 + 0) * 80 + kk] = f2b(v0);
    T[(nn0 + 1) * 80 + kk] = f2b(v1);
    T[(nn0 + 2) * 80 + kk] = f2b(v2);
    T[(nn0 + 3) * 80 + kk] = f2b(v3);
  }
  __syncthreads();
  // write 64(n) x 64(k) coalesced as u16x8
#pragma unroll
  for (int p = 0; p < 2; ++p) {
    int nn = p * 32 + (t >> 3), k0 = (t & 7) * 8;
    u16x8 o = *(const u16x8*)(T + nn * 80 + k0);
    *(u16x8*)(dst + dbase + (size_t)nn * dstride + k0) = o;
  }
}

// Small params -> canonical bf16 (u16 offsets):
// WO_B 0 | LN1S 6144 | LN1B 12288 | FFB1 18432 | FFB2 43008
// LN2S 49152 | LN2B 55296 | OW 61440 | OB 77824 | total 77840
__global__ __launch_bounds__(256) void pack_params(
    const void* wob, const void* l1s, const void* l1b, const void* fb1,
    const void* fb2, const void* l2s, const void* l2b, const void* ow,
    const void* ob, u16* __restrict__ dst, const int* __restrict__ fl) {
  const int f32 = *fl;
  int idx = blockIdx.x * 256 + threadIdx.x;
  if (idx >= 77840) return;
  float v;
  if      (idx < 6144)  v = gload(wob, idx, f32);
  else if (idx < 12288) v = gload(l1s, idx - 6144, f32);
  else if (idx < 18432) v = gload(l1b, idx - 12288, f32);
  else if (idx < 43008) v = gload(fb1, idx - 18432, f32);
  else if (idx < 49152) v = gload(fb2, idx - 43008, f32);
  else if (idx < 55296) v = gload(l2s, idx - 49152, f32);
  else if (idx < 61440) v = gload(l2b, idx - 55296, f32);
  else if (idx < 77824) v = gload(ow,  idx - 61440, f32);
  else                  v = gload(ob,  idx - 77824, f32);
  dst[idx] = f2b(v);
}

// ---------------------------------------------------------------------------
// m97 GEMM: C[M,N] = A[M,K](bf16) * Bt[N,K]^T(bf16); 128x128 tile, BK=32,
// 4 waves (2x2 of 64x64), global_load_lds width-16 staging.
// MODE 1: outf = C + bias (fp32)   MODE 2: o0 = bf16(relu(C + bias))
// MODE 3: full-batch QKV scatter: q->o0[b,h,l,d], k->o1[...], v->o2[b,h,d,l]
template <int MODE>
__global__ __launch_bounds__(256) void gemm_t(
    const u16* __restrict__ A, const u16* __restrict__ Bt, int K, int N,
    const u16* __restrict__ bias, float* __restrict__ outf,
    u16* __restrict__ o0, u16* __restrict__ o1, u16* __restrict__ o2) {
  __shared__ __align__(16) u16 Al[4096];   // 128 rows x 32 k
  __shared__ __align__(16) u16 Bl[4096];
  const int tid = threadIdx.x;
  const int wave = tid >> 6, lane = tid & 63;
  const int quad = lane >> 4, ln = lane & 15;
  const int bm = blockIdx.y, bn = blockIdx.x;
  const int wr = wave >> 1, wc = wave & 1;

  const int e0 = tid * 8;            // staging round 0: elements [0,2048)
  const int e1 = 2048 + tid * 8;     // round 1: [2048,4096)
  const u16* a0 = A + (size_t)(bm * 128 + (e0 >> 5)) * K + (e0 & 31);
  const u16* a1 = A + (size_t)(bm * 128 + (e1 >> 5)) * K + (e1 & 31);
  const u16* b0 = Bt + (size_t)(bn * 128 + (e0 >> 5)) * K + (e0 & 31);
  const u16* b1 = Bt + (size_t)(bn * 128 + (e1 >> 5)) * K + (e1 & 31);
  char* lA0 = (char*)Al + wave * 1024;          // wave-uniform LDS bases
  char* lA1 = (char*)Al + 4096 + wave * 1024;
  char* lB0 = (char*)Bl + wave * 1024;
  char* lB1 = (char*)Bl + 4096 + wave * 1024;

  f32x4 acc[4][4] = {};
  const int nk = K >> 5;
  for (int kt = 0; kt < nk; ++kt) {
    gl_lds16(a0, lA0); gl_lds16(a1, lA1);
    gl_lds16(b0, lB0); gl_lds16(b1, lB1);
    a0 += 32; a1 += 32; b0 += 32; b1 += 32;
    __syncthreads();                            // drains vmcnt before barrier
    s16x8 af[4], bf[4];
#pragma unroll
    for (int mt = 0; mt < 4; ++mt)
      af[mt] = *(const s16x8*)(Al + (wr * 64 + mt * 16 + ln) * 32 + quad * 8);
#pragma unroll
    for (int nt = 0; nt < 4; ++nt)
      bf[nt] = *(const s16x8*)(Bl + (wc * 64 + nt * 16 + ln) * 32 + quad * 8);
#pragma unroll
    for (int mt = 0; mt < 4; ++mt)
#pragma unroll
      for (int nt = 0; nt < 4; ++nt)
        acc[mt][nt] = MFMA16(af[mt], bf[nt], acc[mt][nt]);
    __syncthreads();
  }

#pragma unroll
  for (int mt = 0; mt < 4; ++mt) {
    int rowb = bm * 128 + wr * 64 + mt * 16 + quad * 4;   // + reg = row (m89 C layout)
#pragma unroll
    for (int nt = 0; nt < 4; ++nt) {
      int col = bn * 128 + wc * 64 + nt * 16 + ln;
      f32x4 c = acc[mt][nt];
      if (MODE == 3) {
        int which = col >> 10, hh = (col >> 6) & 15, d = col & 63;
#pragma unroll
        for (int r = 0; r < 4; ++r) {
          int row = rowb + r;
          int b = row >> 10, l = row & 1023;
          if (which == 0)      o0[((size_t)(b * 16 + hh) * 1024 + l) * 64 + d] = f2b(c[r]);
          else if (which == 1) o1[((size_t)(b * 16 + hh) * 1024 + l) * 64 + d] = f2b(c[r]);
          else                 o2[((size_t)(b * 16 + hh) * 64 + d) * 1024 + l] = f2b(c[r]);
        }
      } else if (MODE == 1) {
        float bv = b2f(bias[col]);
#pragma unroll
        for (int r = 0; r < 4; ++r)
          outf[(size_t)(rowb + r) * N + col] = c[r] + bv;
      } else {  // MODE 2
        float bv = b2f(bias[col]);
#pragma unroll
        for (int r = 0; r < 4; ++r) {
          float y = c[r] + bv;
          o0[(size_t)(rowb + r) * N + col] = f2b(y > 0.0f ? y : 0.0f);
        }
      }
    }
  }
}

// ---------------------------------------------------------------------------
// Flash attention, full batch: grid (qt=16, bh=128), 256 thr (R4-verified).
#define AST 80
__global__ __launch_bounds__(256) void attn(const u16* __restrict__ q,
                                            const u16* __restrict__ kb,
                                            const u16* __restrict__ vt,
                                            u16* __restrict__ ctx) {
  const int qt = blockIdx.x, bh = blockIdx.y;
  const int b = bh >> 4, hh = bh & 15;
  __shared__ __align__(16) u16 Kl[64 * AST];
  __shared__ __align__(16) u16 Vl[64 * AST];
  __shared__ __align__(16) u16 Pl[64 * AST];
  const int tid = threadIdx.x, wave = tid >> 6, lane = tid & 63;
  const int quad = lane >> 4, ln = lane & 15;
  const u16* qbh = q + (size_t)bh * 65536;
  const u16* kbh = kb + (size_t)bh * 65536;
  const u16* vbh = vt + (size_t)bh * 65536;

  const int qrow = qt * 64 + wave * 16 + ln;
  s16x8 qf0 = *(const s16x8*)(qbh + qrow * 64 + quad * 8);
  s16x8 qf1 = *(const s16x8*)(qbh + qrow * 64 + 32 + quad * 8);

  f32x4 o[4] = {};
  float mrun[4] = {-1e30f, -1e30f, -1e30f, -1e30f};
  float lrun[4] = {0.f, 0.f, 0.f, 0.f};

  for (int kt = 0; kt < 16; ++kt) {
    __syncthreads();
#pragma unroll
    for (int r2 = 0; r2 < 2; ++r2) {
      int off = r2 * 2048 + tid * 8;
      int row = off >> 6, col = off & 63;
      u16x8 kv = *(const u16x8*)(kbh + kt * 4096 + off);
      *(u16x8*)(Kl + row * AST + col) = kv;
      u16x8 vv = *(const u16x8*)(vbh + row * 1024 + kt * 64 + col);
      *(u16x8*)(Vl + row * AST + col) = vv;
    }
    __syncthreads();

    f32x4 s[4] = {};
#pragma unroll
    for (int nt = 0; nt < 4; ++nt) {
      s16x8 kf0 = *(const s16x8*)(Kl + (nt * 16 + ln) * AST + quad * 8);
      s16x8 kf1 = *(const s16x8*)(Kl + (nt * 16 + ln) * AST + 32 + quad * 8);
      s[nt] = MFMA16(qf0, kf0, s[nt]);
      s[nt] = MFMA16(qf1, kf1, s[nt]);
    }

    float mnew[4], alpha[4], rowsum[4];
#pragma unroll
    for (int r = 0; r < 4; ++r) {
      float v = fmaxf(fmaxf(s[0][r], s[1][r]), fmaxf(s[2][r], s[3][r]));
      v = fmaxf(v, __shfl_xor(v, 1)); v = fmaxf(v, __shfl_xor(v, 2));
      v = fmaxf(v, __shfl_xor(v, 4)); v = fmaxf(v, __shfl_xor(v, 8));
      v *= 0.125f;
      mnew[r] = fmaxf(mrun[r], v);
      alpha[r] = __expf(mrun[r] - mnew[r]);
      mrun[r] = mnew[r];
      rowsum[r] = 0.f;
    }
#pragma unroll
    for (int nt = 0; nt < 4; ++nt)
#pragma unroll
      for (int r = 0; r < 4; ++r) {
        float p = __expf(s[nt][r] * 0.125f - mnew[r]);
        rowsum[r] += p;
        Pl[(wave * 16 + quad * 4 + r) * AST + nt * 16 + ln] = f2b(p);
      }
#pragma unroll
    for (int r = 0; r < 4; ++r) {
      float t = rowsum[r];
      t += __shfl_xor(t, 1); t += __shfl_xor(t, 2);
      t += __shfl_xor(t, 4); t += __shfl_xor(t, 8);
      lrun[r] = lrun[r] * alpha[r] + t;
      o[0][r] *= alpha[r]; o[1][r] *= alpha[r];
      o[2][r] *= alpha[r]; o[3][r] *= alpha[r];
    }
    __syncthreads();

#pragma unroll
    for (int ks = 0; ks < 2; ++ks) {
      s16x8 pf = *(const s16x8*)(Pl + (wave * 16 + ln) * AST + ks * 32 + quad * 8);
#pragma unroll
      for (int dt = 0; dt < 4; ++dt) {
        s16x8 vf = *(const s16x8*)(Vl + (dt * 16 + ln) * AST + ks * 32 + quad * 8);
        o[dt] = MFMA16(pf, vf, o[dt]);
      }
    }
  }

#pragma unroll
  for (int dt = 0; dt < 4; ++dt)
#pragma unroll
    for (int r = 0; r < 4; ++r) {
      int l = qt * 64 + wave * 16 + quad * 4 + r;
      ctx[((size_t)(b * 1024 + l)) * 1024 + hh * 64 + dt * 16 + ln] = f2b(o[dt][r] / lrun[r]);
    }
}

// ---------------------------------------------------------------------------
__device__ __forceinline__ float block_sum(float v, float* red, int wave, int lane) {
  v += __shfl_xor(v, 32); v += __shfl_xor(v, 16); v += __shfl_xor(v, 8);
  v += __shfl_xor(v, 4);  v += __shfl_xor(v, 2);  v += __shfl_xor(v, 1);
  if (lane == 0) red[wave] = v;
  __syncthreads();
  float s = red[0] + red[1] + red[2] + red[3];
  __syncthreads();
  return s;
}

// Residual + LayerNorm: h = LN(h+delta)*s + b ; writes fp32 master + bf16 shadow
__global__ __launch_bounds__(256) void ln_kernel(float* __restrict__ h,
                                                 const float* __restrict__ delta,
                                                 const u16* __restrict__ sc,
                                                 const u16* __restrict__ bs,
                                                 u16* __restrict__ hb) {
  __shared__ float red[4];
  const int row = blockIdx.x, t = threadIdx.x;
  const int wave = t >> 6, lane = t & 63;
  float* hr = h + (size_t)row * 1024;
  const float* dr = delta + (size_t)row * 1024;
  float x0 = hr[t] + dr[t];
  float x1 = hr[t + 256] + dr[t + 256];
  float x2 = hr[t + 512] + dr[t + 512];
  float x3 = hr[t + 768] + dr[t + 768];
  float mean = block_sum(x0 + x1 + x2 + x3, red, wave, lane) * (1.0f / 1024.0f);
  float d0 = x0 - mean, d1 = x1 - mean, d2 = x2 - mean, d3 = x3 - mean;
  float var = block_sum(d0 * d0 + d1 * d1 + d2 * d2 + d3 * d3, red, wave, lane) * (1.0f / 1024.0f);
  float inv = rsqrtf(var + 1e-5f);
  u16* hbr = hb + (size_t)row * 1024;
  float y;
  y = d0 * inv * b2f(sc[t])       + b2f(bs[t]);       hr[t] = y;       hbr[t] = f2b(y);
  y = d1 * inv * b2f(sc[t + 256]) + b2f(bs[t + 256]); hr[t + 256] = y; hbr[t + 256] = f2b(y);
  y = d2 * inv * b2f(sc[t + 512]) + b2f(bs[t + 512]); hr[t + 512] = y; hbr[t + 512] = f2b(y);
  y = d3 * inv * b2f(sc[t + 768]) + b2f(bs[t + 768]); hr[t + 768] = y; hbr[t + 768] = f2b(y);
}

// ---------------------------------------------------------------------------
__global__ __launch_bounds__(128) void head_kernel(const float* __restrict__ h,
                                                   const u16* __restrict__ ow,
                                                   const u16* __restrict__ ob,
                                                   void* __restrict__ out,
                                                   const int* __restrict__ fl) {
  const int t = threadIdx.x;          // 8 b x 16 actions
  const int b = t >> 4, a = t & 15;
  const float* hr = h + ((size_t)(b * 1024 + 1023)) * 1024;
  float acc = 0.f;
  for (int d = 0; d < 1024; ++d) acc += hr[d] * b2f(ow[d * 16 + a]);
  acc += b2f(ob[a]);
  float m = acc;
  m = fmaxf(m, __shfl_xor(m, 1)); m = fmaxf(m, __shfl_xor(m, 2));
  m = fmaxf(m, __shfl_xor(m, 4)); m = fmaxf(m, __shfl_xor(m, 8));
  float e = __expf(acc - m);
  float s = e;
  s += __shfl_xor(s, 1); s += __shfl_xor(s, 2);
  s += __shfl_xor(s, 4); s += __shfl_xor(s, 8);
  float r = acc - m - logf(s);
  if (*fl) ((float*)out)[t] = r;
  else     ((u16*)out)[t] = f2b(r);
}

__global__ void diag_kernel(u16* out, float val) { out[threadIdx.x] = f2b(val); }

// ---------------------------------------------------------------------------
extern "C" void kernel_launch(void* const* d_in, const int* in_sizes, int n_in,
                              void* d_out, int out_size, void* d_ws, size_t ws_size,
                              hipStream_t stream) {
  const int* x      = (const int*)d_in[0];
  const void* embed = d_in[2];
  const void* Wq    = d_in[3];
  const void* Wk    = d_in[4];
  const void* Wv    = d_in[5];
  const void* Wo_w  = d_in[6];
  const void* Wo_b  = d_in[7];
  const void* ln1s  = d_in[8];
  const void* ln1b  = d_in[9];
  const void* ffw1  = d_in[10];
  const void* ffb1  = d_in[11];
  const void* ffw2  = d_in[12];
  const void* ffb2  = d_in[13];
  const void* ln2s  = d_in[14];
  const void* ln2b  = d_in[15];
  const void* ow    = d_in[16];
  const void* ob    = d_in[17];

  // ws map (MiB): hM 0-32 | att 32-64 | hB 64-80 | ctx 80-96 | qb 96-112
  //   kb 112-128 | vtb 128-144 | ff1 144-208 | packs 208-352 (6 x 24MB) | params@352
  const size_t NEEDED = 369360896;   // ~352.3 MiB (R4 fill shows ws ~500 MiB)
  if (ws_size < NEEDED) {
    diag_kernel<<<1, 128, 0, stream>>>((u16*)d_out, (float)(ws_size >> 20));
    return;
  }
  char* ws = (char*)d_ws;
  float* hM   = (float*)(ws + 0);
  float* att  = (float*)(ws + 33554432);
  u16* hB     = (u16*)(ws + 67108864);
  u16* ctx    = (u16*)(ws + 83886080);
  u16* qb     = (u16*)(ws + 100663296);
  u16* kbuf   = (u16*)(ws + 117440512);
  u16* vtb    = (u16*)(ws + 134217728);
  u16* ff1    = (u16*)(ws + 150994944);
  u16* packs  = (u16*)(ws + 218103808);
  u16* params = (u16*)(ws + 369098752);
  int* flag   = (int*)(ws + 369098752 + 160000);

  const int WO_B = 0, LN1S = 6144, LN1B = 12288, FFB1 = 18432, FFB2 = 43008,
            LN2S = 49152, LN2B = 55296, OW = 61440, OB = 77824;
  const size_t LSTRIDE = 12582912;           // per-layer pack stride (u16)
  const size_t P_WO = 3145728, P_FF1 = 4194304, P_FF2 = 8388608;

  detect_dtype<<<1, 256, 0, stream>>>((const u16*)embed, flag);
  pack_params<<<305, 256, 0, stream>>>(Wo_b, ln1s, ln1b, ffb1, ffb2, ln2s, ln2b,
                                       ow, ob, params, flag);
  pack6<<<dim3(16, 48, 6), 256, 0, stream>>>(Wq, Wk, Wv, Wo_w, ffw1, ffw2, packs, 0, flag);
  pack6<<<dim3(16, 16, 6), 256, 0, stream>>>(Wq, Wk, Wv, Wo_w, ffw1, ffw2, packs, 1, flag);
  pack6<<<dim3(16, 64, 6), 256, 0, stream>>>(Wq, Wk, Wv, Wo_w, ffw1, ffw2, packs, 2, flag);
  pack6<<<dim3(64, 16, 6), 256, 0, stream>>>(Wq, Wk, Wv, Wo_w, ffw1, ffw2, packs, 3, flag);
  embed_pe<<<16384, 256, 0, stream>>>(x, embed, hM, hB, flag);

  for (int i = 0; i < 6; ++i) {
    u16* pL = packs + (size_t)i * LSTRIDE;
    // QKV: [8192,1024] x [1024,3072] -> q,k,vT (scatter)
    gemm_t<3><<<dim3(24, 64), 256, 0, stream>>>(hB, pL, 1024, 3072, nullptr,
                                                nullptr, qb, kbuf, vtb);
    attn<<<dim3(16, 128), 256, 0, stream>>>(qb, kbuf, vtb, ctx);
    // Wo: [8192,1024] x [1024,1024] + bias -> fp32 att
    gemm_t<1><<<dim3(8, 64), 256, 0, stream>>>(ctx, pL + P_WO, 1024, 1024,
                                               params + WO_B + i * 1024,
                                               att, nullptr, nullptr, nullptr);
    ln_kernel<<<8192, 256, 0, stream>>>(hM, att, params + LN1S + i * 1024,
                                        params + LN1B + i * 1024, hB);
    // FF1: [8192,1024] x [1024,4096] + bias + relu -> bf16 ff1
    gemm_t<2><<<dim3(32, 64), 256, 0, stream>>>(hB, pL + P_FF1, 1024, 4096,
                                                params + FFB1 + i * 4096,
                                                nullptr, ff1, nullptr, nullptr);
    // FF2: [8192,4096] x [4096,1024] + bias -> fp32 att
    gemm_t<1><<<dim3(8, 64), 256, 0, stream>>>(ff1, pL + P_FF2, 4096, 1024,
                                               params + FFB2 + i * 1024,
                                               att, nullptr, nullptr, nullptr);
    ln_kernel<<<8192, 256, 0, stream>>>(hM, att, params + LN2S + i * 1024,
                                        params + LN2B + i * 1024, hB);
  }

  head_kernel<<<1, 128, 0, stream>>>(hM, params + OW, params + OB, d_out, flag);
}